// Round 1
// baseline (39.952 us; speedup 1.0000x reference)
//
#include <hip/hip_runtime.h>
#include <math.h>

#define N_ROWS    8192
#define DIM       128
#define NCLASS    100
#define TEMP      0.5f
#define EPS       1e-8f

// ws layout (floats):
//   [0 .. NCLASS*DIM)            : C  (per-class sums of normalized rows)
//   [NCLASS*DIM .. NCLASS*DIM+DIM): S (total sum vector)
#define C_OFF 0
#define S_OFF (NCLASS * DIM)

__global__ void ntx_zero(float* C, float* out) {
    int i = blockIdx.x * blockDim.x + threadIdx.x;
    if (i < NCLASS * DIM) C[i] = 0.0f;
    if (i == 0) out[0] = 0.0f;
}

// One wave (64 lanes) per row: each lane owns dims {lane, lane+64}.
__global__ void ntx_class_sums(const float* __restrict__ z,
                               const int* __restrict__ labels,
                               float* __restrict__ C) {
    const int lane  = threadIdx.x & 63;
    const int wave  = (blockIdx.x * blockDim.x + threadIdx.x) >> 6;
    const int nwave = (gridDim.x * blockDim.x) >> 6;

    for (int row = wave; row < N_ROWS; row += nwave) {
        const float* zr = z + (size_t)row * DIM;
        float a = zr[lane];
        float b = zr[lane + 64];
        float ss = a * a + b * b;
        #pragma unroll
        for (int off = 1; off < 64; off <<= 1)
            ss += __shfl_xor(ss, off);
        float inv = 1.0f / fmaxf(sqrtf(ss), EPS);
        int lbl = labels[row];
        atomicAdd(&C[lbl * DIM + lane],      a * inv);
        atomicAdd(&C[lbl * DIM + lane + 64], b * inv);
    }
}

// S[d] = sum_c C[c][d].  One block of 128 threads.
__global__ void ntx_total_sum(const float* __restrict__ C,
                              float* __restrict__ S) {
    int d = threadIdx.x;
    float s = 0.0f;
    for (int c = 0; c < NCLASS; ++c) s += C[c * DIM + d];
    S[d] = s;
}

// One wave per row: loss_i = -log(pos_i / tot_i); accumulate mean into out.
__global__ void ntx_loss(const float* __restrict__ z,
                         const int* __restrict__ labels,
                         const float* __restrict__ C,
                         const float* __restrict__ S,
                         float* __restrict__ out) {
    const int lane  = threadIdx.x & 63;
    const int wave  = (blockIdx.x * blockDim.x + threadIdx.x) >> 6;
    const int nwave = (gridDim.x * blockDim.x) >> 6;

    float acc = 0.0f;
    for (int row = wave; row < N_ROWS; row += nwave) {
        const float* zr = z + (size_t)row * DIM;
        float a = zr[lane];
        float b = zr[lane + 64];
        int lbl = labels[row];
        const float* Cc = C + lbl * DIM;

        float ss = a * a + b * b;
        float dc = a * Cc[lane] + b * Cc[lane + 64];
        float dt = a * S[lane]  + b * S[lane + 64];
        #pragma unroll
        for (int off = 1; off < 64; off <<= 1) {
            ss += __shfl_xor(ss, off);
            dc += __shfl_xor(dc, off);
            dt += __shfl_xor(dt, off);
        }
        float inv  = 1.0f / fmaxf(sqrtf(ss), EPS);
        float self = ss * inv * inv;                 // zn_i . zn_i  (== 1)
        float pos  = (dc * inv - self) * (1.0f / TEMP);
        float tot  = (dt * inv) * (1.0f / TEMP);
        acc += -logf(pos / tot);
    }
    if (lane == 0 && acc != 0.0f)
        atomicAdd(out, acc * (1.0f / (float)N_ROWS));
}

extern "C" void kernel_launch(void* const* d_in, const int* in_sizes, int n_in,
                              void* d_out, int out_size, void* d_ws, size_t ws_size,
                              hipStream_t stream) {
    const float* z      = (const float*)d_in[0];
    const int*   labels = (const int*)d_in[1];
    float* out = (float*)d_out;
    float* ws  = (float*)d_ws;
    float* C = ws + C_OFF;
    float* S = ws + S_OFF;

    (void)in_sizes; (void)n_in; (void)out_size; (void)ws_size;

    // 1. zero C and out
    ntx_zero<<<(NCLASS * DIM + 255) / 256, 256, 0, stream>>>(C, out);
    // 2. per-class sums of normalized rows (1024 waves, 8 rows each)
    ntx_class_sums<<<256, 256, 0, stream>>>(z, labels, C);
    // 3. total sum vector
    ntx_total_sum<<<1, DIM, 0, stream>>>(C, S);
    // 4. per-row loss + mean reduction
    ntx_loss<<<256, 256, 0, stream>>>(z, labels, C, S, out);
}